// Round 2
// baseline (3377.872 us; speedup 1.0000x reference)
//
#include <hip/hip_runtime.h>
#include <hip/hip_cooperative_groups.h>
#include <cstdint>

namespace cg = cooperative_groups;

#define B_ 32
#define T_ 40
#define P_ 12
#define E_ 2048
#define H_ 1024
#define BP 384      // B_*P_
#define M_ 15360    // B_*T_*P_

typedef _Float16 f16;
typedef _Float16 f16x8 __attribute__((ext_vector_type(8)));
typedef float f32x4 __attribute__((ext_vector_type(4)));

// ---- async global->LDS, 16B per lane (dest = wave-uniform base + lane*16) ----
__device__ __forceinline__ void cp16(const void* g, void* l) {
    auto gp = (const __attribute__((address_space(1))) uint32_t*)(uintptr_t)g;
    auto lp = (__attribute__((address_space(3))) uint32_t*)(uint32_t)(uintptr_t)l;
    __builtin_amdgcn_global_load_lds(gp, lp, 16, 0, 0);
}

__device__ __forceinline__ float fast_tanh(float x) {
    return 1.f - 2.f / (__expf(2.f * x) + 1.f);
}
__device__ __forceinline__ float fast_sig(float x) {
    return 1.f / (1.f + __expf(-x));
}

// ---- fp32 -> fp16 conversion, 8 elems/thread ----
__global__ __launch_bounds__(256) void cvt_f32_f16(const float* __restrict__ in,
                                                   f16* __restrict__ out, int n8) {
    int i = blockIdx.x * 256 + threadIdx.x;
    if (i >= n8) return;
    const float4* in4 = (const float4*)in;
    float4 a = in4[2 * i], b = in4[2 * i + 1];
    f16x8 o = {(f16)a.x, (f16)a.y, (f16)a.z, (f16)a.w,
               (f16)b.x, (f16)b.y, (f16)b.z, (f16)b.w};
    ((f16x8*)out)[i] = o;
}

// ---- 128x128 tile NT-GEMM:  C[m,n] = sum_k A[m,k]*Bm[n,k]  (+bias, epilogue) ----
// LDS is fragment-major: slice s, lane l holds A[s*16 + (l&15)][(l>>4)*8 ..+8]
// at byte offset s*1024 + l*16  ->  ds_read_b128 conflict-free.
// EPI 0: out[m*N+n] = (f16)tanh(c+bias[n])            (embed -> x16)
// EPI 1: out[(t*BP + b*12 + p)*N + n] = (f16)(c+bias[n])   (gx, remapped to [T][BP][3H])
template <int EPI>
__global__ __launch_bounds__(256) void gemm128(const f16* __restrict__ A,
                                               const f16* __restrict__ Bm,
                                               const float* __restrict__ bias,
                                               f16* __restrict__ out, int K, int N) {
    __shared__ f16 As[128 * 32];
    __shared__ f16 Bs[128 * 32];
    const int tid = threadIdx.x;
    const int w = tid >> 6, l = tid & 63;
    const int wm = w >> 1, wn = w & 1;      // 2x2 waves of 64x64
    const long arow0 = (long)blockIdx.x * 128;
    const long brow0 = (long)blockIdx.y * 128;
    const int srow = l & 15, scol = (l >> 4) * 8;   // fragment-major staging

    f32x4 acc[4][4] = {};

    for (int k0 = 0; k0 < K; k0 += 32) {
        __syncthreads();
#pragma unroll
        for (int s = 0; s < 2; ++s) {
            int slice = w + s * 4;          // 0..7, wave-uniform
            cp16(A + (arow0 + slice * 16 + srow) * (long)K + k0 + scol,
                 (void*)(As + slice * 512));
            cp16(Bm + (brow0 + slice * 16 + srow) * (long)K + k0 + scol,
                 (void*)(Bs + slice * 512));
        }
        __syncthreads();
        f16x8 af[4], bf[4];
#pragma unroll
        for (int i = 0; i < 4; ++i)
            af[i] = *(const f16x8*)(As + ((wm * 4 + i) * 64 + l) * 8);
#pragma unroll
        for (int j = 0; j < 4; ++j)
            bf[j] = *(const f16x8*)(Bs + ((wn * 4 + j) * 64 + l) * 8);
#pragma unroll
        for (int i = 0; i < 4; ++i)
#pragma unroll
            for (int j = 0; j < 4; ++j)
                acc[i][j] = __builtin_amdgcn_mfma_f32_16x16x32_f16(af[i], bf[j], acc[i][j], 0, 0, 0);
    }

    const int colq = l & 15, rowq = (l >> 4) * 4;
#pragma unroll
    for (int i = 0; i < 4; ++i)
#pragma unroll
        for (int j = 0; j < 4; ++j)
#pragma unroll
            for (int r = 0; r < 4; ++r) {
                long m = arow0 + wm * 64 + i * 16 + rowq + r;
                int n = (int)brow0 + wn * 64 + j * 16 + colq;
                float v = acc[i][j][r] + bias[n];
                if (EPI == 0) {
                    out[m * N + n] = (f16)fast_tanh(v);
                } else {
                    int b = (int)(m / (T_ * P_));
                    int rem = (int)(m % (T_ * P_));
                    int t = rem / P_, p = rem % P_;
                    out[((long)t * BP + b * P_ + p) * N + n] = (f16)v;
                }
            }
}

// ---- persistent cooperative GRU: all 40 steps in one kernel ----
// grid 256 blocks (1/CU), block 256 thr. Block owns rows [m0,m0+96), cols [n0,n0+16).
// W_hh fragments (3 bands x 16 cols x K=1024 = 96 KB) LDS-resident across steps.
// Wave 3 = producer (h chunks via global_load_lds, gx tile); waves 0-2 = MFMA.
// h_prev master in fp32 registers; h published as fp16 ping-pong in d_ws.
__global__ __launch_bounds__(256) void gru_persist(const f16* __restrict__ gx16,
                                                   const f16* __restrict__ whh16,
                                                   const float* __restrict__ bhh,
                                                   f16* __restrict__ hbuf,
                                                   f16* __restrict__ hid16) {
    __shared__ f16 wlds[3 * 32 * 64 * 8];     // 96 KB  [g][ks][lane][8]
    __shared__ f16 hlds[2 * 12 * 64 * 8];     // 24 KB  [buf][slot=ks*6+i][lane][8]
    __shared__ float bandout[3 * 96 * 16];    // 18 KB  [g][row][col]
    __shared__ f16 gxlds[3 * 96 * 16];        //  9 KB  [g][row][col]
    const int tid = threadIdx.x;
    const int w = tid >> 6, l = tid & 63;
    const int m0 = (blockIdx.x & 3) * 96;     // 4 row groups
    const int n0 = (blockIdx.x >> 2) * 16;    // 64 col groups

    for (int i = tid; i < 3 * 96 * 16; i += 256) bandout[i] = 0.f;
    // stage W_hh fragments once (fragment-major, conflict-free reads later)
    for (int idx = tid; idx < 6144; idx += 256) {
        int g = idx >> 11, ks = (idx >> 6) & 31, ll = idx & 63;
        *(f16x8*)(wlds + idx * 8) =
            *(const f16x8*)(whh16 + ((long)(g * H_ + n0 + (ll & 15))) * H_ + ks * 32 + (ll >> 4) * 8);
    }
    const int ec = tid & 15, er = tid >> 4;
    const float bhr = bhh[n0 + ec], bhz = bhh[H_ + n0 + ec], bhn = bhh[2 * H_ + n0 + ec];
    float hprev[6] = {0.f, 0.f, 0.f, 0.f, 0.f, 0.f};
    cg::grid_group grid = cg::this_grid();
    __syncthreads();

    for (int t = 0; t < T_; ++t) {
        const f16* hin = hbuf + (size_t)(t & 1) * (BP * H_);
        f16* hout = hbuf + (size_t)((t + 1) & 1) * (BP * H_);
        if (t > 0) {
            f32x4 acc[3][2] = {};
            if (w == 3) {   // prologue: chunk 0 -> buf 0
#pragma unroll
                for (int s = 0; s < 12; ++s) {
                    int ks = s / 6, i = s % 6;
                    cp16(hin + (m0 + i * 16 + (l & 15)) * H_ + ks * 32 + (l >> 4) * 8,
                         (void*)(hlds + s * 512));
                }
            }
            __syncthreads();
            for (int kc = 0; kc < 16; ++kc) {
                int cur = kc & 1;
                if (w == 3) {
                    if (kc < 15) {
                        int kn = kc + 1;
#pragma unroll
                        for (int s = 0; s < 12; ++s) {
                            int ks = s / 6, i = s % 6;
                            cp16(hin + (m0 + i * 16 + (l & 15)) * H_ + kn * 64 + ks * 32 + (l >> 4) * 8,
                                 (void*)(hlds + ((kn & 1) * 12 + s) * 512 + l * 0));
                        }
                    }
                    if (kc == 0) {   // prefetch gx tile for this step
#pragma unroll
                        for (int g = 0; g < 3; ++g)
#pragma unroll
                            for (int rb = 0; rb < 3; ++rb)
                                cp16(gx16 + ((long)t * BP + m0 + rb * 32 + (l >> 1)) * 3072 + g * H_ + n0 + (l & 1) * 8,
                                     (void*)(gxlds + (g * 96 + rb * 32) * 16));
                    }
                } else {
#pragma unroll
                    for (int ks = 0; ks < 2; ++ks) {
                        f16x8 bf[3], af[2];
#pragma unroll
                        for (int g = 0; g < 3; ++g)
                            bf[g] = *(const f16x8*)(wlds + ((g * 32 + kc * 2 + ks) * 64 + l) * 8);
#pragma unroll
                        for (int mi = 0; mi < 2; ++mi)
                            af[mi] = *(const f16x8*)(hlds + ((cur * 12 + ks * 6 + (w * 2 + mi)) * 64 + l) * 8);
#pragma unroll
                        for (int g = 0; g < 3; ++g)
#pragma unroll
                            for (int mi = 0; mi < 2; ++mi)
                                acc[g][mi] = __builtin_amdgcn_mfma_f32_16x16x32_f16(af[mi], bf[g], acc[g][mi], 0, 0, 0);
                    }
                }
                __syncthreads();
            }
            if (w < 3) {
#pragma unroll
                for (int g = 0; g < 3; ++g)
#pragma unroll
                    for (int mi = 0; mi < 2; ++mi)
#pragma unroll
                        for (int r = 0; r < 4; ++r)
                            bandout[g * 1536 + ((w * 2 + mi) * 16 + (l >> 4) * 4 + r) * 16 + (l & 15)] = acc[g][mi][r];
            }
            __syncthreads();
        } else {
            if (w == 3) {
#pragma unroll
                for (int g = 0; g < 3; ++g)
#pragma unroll
                    for (int rb = 0; rb < 3; ++rb)
                        cp16(gx16 + ((long)t * BP + m0 + rb * 32 + (l >> 1)) * 3072 + g * H_ + n0 + (l & 1) * 8,
                             (void*)(gxlds + (g * 96 + rb * 32) * 16));
            }
            __syncthreads();
        }
        // epilogue: gates + h update; this thread owns (rows j*16+er, col ec)
#pragma unroll
        for (int j = 0; j < 6; ++j) {
            int m = j * 16 + er;
            int mg = m0 + m;
            float rr = bandout[0 * 1536 + m * 16 + ec] + bhr;
            float zz = bandout[1 * 1536 + m * 16 + ec] + bhz;
            float nn = bandout[2 * 1536 + m * 16 + ec] + bhn;
            float xr = (float)gxlds[(0 * 96 + m) * 16 + ec];
            float xz = (float)gxlds[(1 * 96 + m) * 16 + ec];
            float xn = (float)gxlds[(2 * 96 + m) * 16 + ec];
            float r_ = fast_sig(xr + rr);
            float z_ = fast_sig(xz + zz);
            float n_ = fast_tanh(xn + r_ * nn);
            float hnew = (1.f - z_) * n_ + z_ * hprev[j];
            hprev[j] = hnew;
            hout[mg * H_ + n0 + ec] = (f16)hnew;
            int b = mg / P_, p = mg % P_;
            hid16[(((long)b * T_ + t) * P_ + p) * H_ + n0 + ec] = (f16)hnew;
        }
        __threadfence();
        if (t != T_ - 1) grid.sync();
    }
}

// ---- per-(b,t): 12x9 action logits, maxpool over P, 8 activity logits ----
__global__ __launch_bounds__(256) void logits_kernel(const f16* __restrict__ hid16,
                                                     const float* __restrict__ W_act,
                                                     const float* __restrict__ b_act,
                                                     const float* __restrict__ W_activ,
                                                     const float* __restrict__ b_activ,
                                                     float* __restrict__ out) {
    __shared__ f16 hs[P_ * H_];
    __shared__ float pooled[H_];
    const int bt = blockIdx.x;           // b*T_ + t
    const int tid = threadIdx.x, w = tid >> 6, l = tid & 63;

    const f16x8* src = (const f16x8*)(hid16 + (long)bt * P_ * H_);
    f16x8* dst = (f16x8*)hs;
    for (int i = tid; i < P_ * H_ / 8; i += 256) dst[i] = src[i];
    __syncthreads();

    for (int i = tid; i < H_; i += 256) {
        float mx = (float)hs[i];
#pragma unroll
        for (int p = 1; p < P_; ++p) mx = fmaxf(mx, (float)hs[p * H_ + i]);
        pooled[i] = mx;
    }
    __syncthreads();

    for (int j = w; j < 108; j += 4) {
        int p = j / 9, a = j % 9;
        float s = 0.f;
#pragma unroll
        for (int it = 0; it < 16; ++it) {
            int idx = l + it * 64;
            s += (float)hs[p * H_ + idx] * W_act[a * H_ + idx];
        }
#pragma unroll
        for (int off = 32; off > 0; off >>= 1) s += __shfl_down(s, off);
        if (l == 0) out[((long)bt * P_ + p) * 9 + a] = s + b_act[a];
    }
    for (int j = w; j < 8; j += 4) {
        float s = 0.f;
#pragma unroll
        for (int it = 0; it < 16; ++it) {
            int idx = l + it * 64;
            s += pooled[idx] * W_activ[j * H_ + idx];
        }
#pragma unroll
        for (int off = 32; off > 0; off >>= 1) s += __shfl_down(s, off);
        if (l == 0) out[(long)M_ * 9 + (long)bt * 8 + j] = s + b_activ[j];
    }
}

extern "C" void kernel_launch(void* const* d_in, const int* in_sizes, int n_in,
                              void* d_out, int out_size, void* d_ws, size_t ws_size,
                              hipStream_t stream) {
    const float* feature = (const float*)d_in[0];
    const float* W_embed = (const float*)d_in[1];
    const float* b_embed = (const float*)d_in[2];
    const float* W_ih    = (const float*)d_in[3];
    const float* W_hh    = (const float*)d_in[4];
    const float* b_ih    = (const float*)d_in[5];
    const float* b_hh    = (const float*)d_in[6];
    const float* W_act   = (const float*)d_in[7];
    const float* b_act   = (const float*)d_in[8];
    const float* W_activ = (const float*)d_in[9];
    const float* b_activ = (const float*)d_in[10];
    float* out = (float*)d_out;

    char* ws = (char*)d_ws;
    size_t off = 0;
    auto alloc = [&](size_t bytes) {
        void* p = ws + off;
        off = (off + bytes + 255) & ~(size_t)255;
        return p;
    };
    f16* feat16 = (f16*)alloc((size_t)M_ * E_ * 2);        // 62.9 MB
    f16* wE16   = (f16*)alloc((size_t)H_ * E_ * 2);        //  4.2 MB
    f16* wIH16  = (f16*)alloc((size_t)3 * H_ * H_ * 2);    //  6.3 MB
    f16* wHH16  = (f16*)alloc((size_t)3 * H_ * H_ * 2);    //  6.3 MB
    f16* x16    = (f16*)alloc((size_t)M_ * H_ * 2);        // 31.5 MB
    f16* gx16   = (f16*)alloc((size_t)M_ * 3 * H_ * 2);    // 94.4 MB
    f16* hbuf   = (f16*)alloc((size_t)2 * BP * H_ * 2);    //  1.5 MB
    f16* hid16  = (f16*)alloc((size_t)M_ * H_ * 2);        // 31.5 MB
    (void)ws_size; (void)in_sizes; (void)n_in; (void)out_size;

    cvt_f32_f16<<<(M_ * E_) / 2048, 256, 0, stream>>>(feature, feat16, (M_ * E_) / 8);
    cvt_f32_f16<<<(H_ * E_) / 2048, 256, 0, stream>>>(W_embed, wE16, (H_ * E_) / 8);
    cvt_f32_f16<<<(3 * H_ * H_) / 2048, 256, 0, stream>>>(W_ih, wIH16, (3 * H_ * H_) / 8);
    cvt_f32_f16<<<(3 * H_ * H_) / 2048, 256, 0, stream>>>(W_hh, wHH16, (3 * H_ * H_) / 8);

    gemm128<0><<<dim3(M_ / 128, H_ / 128), 256, 0, stream>>>(feat16, wE16, b_embed, x16, E_, H_);
    gemm128<1><<<dim3(M_ / 128, (3 * H_) / 128), 256, 0, stream>>>(x16, wIH16, b_ih, gx16, H_, 3 * H_);

    void* args[] = {(void*)&gx16, (void*)&wHH16, (void*)&b_hh, (void*)&hbuf, (void*)&hid16};
    hipLaunchCooperativeKernel((const void*)gru_persist, dim3(256), dim3(256), args, 0, stream);

    logits_kernel<<<B_ * T_, 256, 0, stream>>>(hid16, W_act, b_act, W_activ, b_activ, out);
}

// Round 3
// 1566.815 us; speedup vs baseline: 2.1559x; 2.1559x over previous
//
#include <hip/hip_runtime.h>
#include <cstdint>

#define B_ 32
#define T_ 40
#define P_ 12
#define E_ 2048
#define H_ 1024
#define BP 384      // B_*P_
#define M_ 15360    // B_*T_*P_

typedef _Float16 f16;
typedef _Float16 f16x8 __attribute__((ext_vector_type(8)));
typedef float f32x4 __attribute__((ext_vector_type(4)));

// ---- async global->LDS, 16B per lane (dest = wave-uniform base + lane*16) ----
__device__ __forceinline__ void cp16(const void* g, void* l) {
    auto gp = (const __attribute__((address_space(1))) uint32_t*)(uintptr_t)g;
    auto lp = (__attribute__((address_space(3))) uint32_t*)(uint32_t)(uintptr_t)l;
    __builtin_amdgcn_global_load_lds(gp, lp, 16, 0, 0);
}

__device__ __forceinline__ float fast_tanh(float x) {
    return 1.f - 2.f / (__expf(2.f * x) + 1.f);
}
__device__ __forceinline__ float fast_sig(float x) {
    return 1.f / (1.f + __expf(-x));
}

// ---- fp32 -> fp16 conversion, 8 elems/thread ----
__global__ __launch_bounds__(256) void cvt_f32_f16(const float* __restrict__ in,
                                                   f16* __restrict__ out, int n8) {
    int i = blockIdx.x * 256 + threadIdx.x;
    if (i >= n8) return;
    const float4* in4 = (const float4*)in;
    float4 a = in4[2 * i], b = in4[2 * i + 1];
    f16x8 o = {(f16)a.x, (f16)a.y, (f16)a.z, (f16)a.w,
               (f16)b.x, (f16)b.y, (f16)b.z, (f16)b.w};
    ((f16x8*)out)[i] = o;
}

// ---- 128x128 tile NT-GEMM:  C[m,n] = sum_k A[m,k]*Bm[n,k]  (+bias, epilogue) ----
// LDS fragment-major: slice s, lane l holds A[s*16 + (l&15)][(l>>4)*8 ..+8] at
// byte offset s*1024 + l*16  ->  ds_read_b128 conflict-free.
// EPI 0: out[m*N+n] = (f16)tanh(c+bias[n])                 (embed -> x16)
// EPI 1: out[(t*BP + b*12 + p)*N + n] = (f16)(c+bias[n])   (gx, remap to [T][BP][3H])
template <int EPI>
__global__ __launch_bounds__(256) void gemm128(const f16* __restrict__ A,
                                               const f16* __restrict__ Bm,
                                               const float* __restrict__ bias,
                                               f16* __restrict__ out, int K, int N) {
    __shared__ f16 As[128 * 32];
    __shared__ f16 Bs[128 * 32];
    const int tid = threadIdx.x;
    const int w = tid >> 6, l = tid & 63;
    const int wm = w >> 1, wn = w & 1;      // 2x2 waves of 64x64
    const long arow0 = (long)blockIdx.x * 128;
    const long brow0 = (long)blockIdx.y * 128;
    const int srow = l & 15, scol = (l >> 4) * 8;   // fragment-major staging

    f32x4 acc[4][4] = {};

    for (int k0 = 0; k0 < K; k0 += 32) {
        __syncthreads();
#pragma unroll
        for (int s = 0; s < 2; ++s) {
            int slice = w + s * 4;          // 0..7, wave-uniform
            cp16(A + (arow0 + slice * 16 + srow) * (long)K + k0 + scol,
                 (void*)(As + slice * 512));
            cp16(Bm + (brow0 + slice * 16 + srow) * (long)K + k0 + scol,
                 (void*)(Bs + slice * 512));
        }
        __syncthreads();
        f16x8 af[4], bf[4];
#pragma unroll
        for (int i = 0; i < 4; ++i)
            af[i] = *(const f16x8*)(As + ((wm * 4 + i) * 64 + l) * 8);
#pragma unroll
        for (int j = 0; j < 4; ++j)
            bf[j] = *(const f16x8*)(Bs + ((wn * 4 + j) * 64 + l) * 8);
#pragma unroll
        for (int i = 0; i < 4; ++i)
#pragma unroll
            for (int j = 0; j < 4; ++j)
                acc[i][j] = __builtin_amdgcn_mfma_f32_16x16x32_f16(af[i], bf[j], acc[i][j], 0, 0, 0);
    }

    const int colq = l & 15, rowq = (l >> 4) * 4;
#pragma unroll
    for (int i = 0; i < 4; ++i)
#pragma unroll
        for (int j = 0; j < 4; ++j)
#pragma unroll
            for (int r = 0; r < 4; ++r) {
                long m = arow0 + wm * 64 + i * 16 + rowq + r;
                int n = (int)brow0 + wn * 64 + j * 16 + colq;
                float v = acc[i][j][r] + bias[n];
                if (EPI == 0) {
                    out[m * N + n] = (f16)fast_tanh(v);
                } else {
                    int b = (int)(m / (T_ * P_));
                    int rem = (int)(m % (T_ * P_));
                    int t = rem / P_, p = rem % P_;
                    out[((long)t * BP + b * P_ + p) * N + n] = (f16)v;
                }
            }
}

// ---- persistent cooperative GRU: all 40 steps in one kernel ----
// grid 256 (1/CU). Block owns rows [m0,m0+96), cols [n0,n0+16); W_hh fragments
// (96 KB) LDS-resident for all steps. Wave 3 = producer (h chunks + gx tile via
// global_load_lds); waves 0-2 = MFMA + in-register gate epilogue (hprev lives in
// their registers). Steps separated by a custom release/acquire grid barrier
// (cg::grid.sync measured ~65 us/sync on gfx950 -- unusable).
__global__ __launch_bounds__(256) void gru_persist(const f16* __restrict__ gx16,
                                                   const f16* __restrict__ whh16,
                                                   const float* __restrict__ bhh,
                                                   f16* __restrict__ hbuf,
                                                   f16* __restrict__ hid16,
                                                   int* __restrict__ bar) {
    __shared__ f16 wlds[3 * 32 * 64 * 8];     // 96 KB  [g][ks][lane][8]
    __shared__ f16 hlds[2 * 12 * 64 * 8];     // 24 KB  [buf][slot=ks*6+i][lane][8]
    __shared__ f16 gxlds[3 * 96 * 16];        //  9 KB  [g][row][col]
    const int tid = threadIdx.x;
    const int w = tid >> 6, l = tid & 63;
    const int m0 = (blockIdx.x & 3) * 96;     // 4 row groups
    const int n0 = (blockIdx.x >> 2) * 16;    // 64 col groups

    // stage W_hh fragments once (fragment-major -> conflict-free ds_read_b128)
    for (int idx = tid; idx < 6144; idx += 256) {
        int g = idx >> 11, ks = (idx >> 6) & 31, ll = idx & 63;
        *(f16x8*)(wlds + idx * 8) =
            *(const f16x8*)(whh16 + ((long)(g * H_ + n0 + (ll & 15))) * H_ + ks * 32 + (ll >> 4) * 8);
    }
    const int colq = l & 15, rowq = (l >> 4) * 4;
    const int col = n0 + colq;
    const float bhr = bhh[col], bhz = bhh[H_ + col], bhn = bhh[2 * H_ + col];
    float hprev[2][4] = {};                   // waves 0-2: 2 row-tiles x 4 rows, 1 col
    __syncthreads();

    for (int t = 0; t < T_; ++t) {
        const f16* hin = hbuf + (size_t)(t & 1) * (BP * H_);
        f16* hout = hbuf + (size_t)((t + 1) & 1) * (BP * H_);
        f32x4 acc[3][2] = {};
        if (t > 0) {
            if (w == 3) {   // prologue: chunk 0 -> buf 0
#pragma unroll
                for (int s = 0; s < 12; ++s) {
                    int ks = s / 6, i = s % 6;
                    cp16(hin + (m0 + i * 16 + (l & 15)) * H_ + ks * 32 + (l >> 4) * 8,
                         (void*)(hlds + s * 512));
                }
            }
            __syncthreads();
            for (int kc = 0; kc < 16; ++kc) {
                int cur = kc & 1;
                if (w == 3) {
                    if (kc < 15) {
                        int kn = kc + 1;
#pragma unroll
                        for (int s = 0; s < 12; ++s) {
                            int ks = s / 6, i = s % 6;
                            cp16(hin + (m0 + i * 16 + (l & 15)) * H_ + kn * 64 + ks * 32 + (l >> 4) * 8,
                                 (void*)(hlds + ((kn & 1) * 12 + s) * 512));
                        }
                    }
                    if (kc == 0) {   // prefetch gx tile for this step
#pragma unroll
                        for (int g = 0; g < 3; ++g)
#pragma unroll
                            for (int rb = 0; rb < 3; ++rb)
                                cp16(gx16 + ((long)t * BP + m0 + rb * 32 + (l >> 1)) * 3072 + g * H_ + n0 + (l & 1) * 8,
                                     (void*)(gxlds + (g * 96 + rb * 32) * 16));
                    }
                } else {
#pragma unroll
                    for (int ks = 0; ks < 2; ++ks) {
                        f16x8 bf[3], af[2];
#pragma unroll
                        for (int g = 0; g < 3; ++g)
                            bf[g] = *(const f16x8*)(wlds + ((g * 32 + kc * 2 + ks) * 64 + l) * 8);
#pragma unroll
                        for (int mi = 0; mi < 2; ++mi)
                            af[mi] = *(const f16x8*)(hlds + ((cur * 12 + ks * 6 + (w * 2 + mi)) * 64 + l) * 8);
#pragma unroll
                        for (int g = 0; g < 3; ++g)
#pragma unroll
                            for (int mi = 0; mi < 2; ++mi)
                                acc[g][mi] = __builtin_amdgcn_mfma_f32_16x16x32_f16(af[mi], bf[g], acc[g][mi], 0, 0, 0);
                    }
                }
                __syncthreads();
            }
        } else {
            if (w == 3) {
#pragma unroll
                for (int g = 0; g < 3; ++g)
#pragma unroll
                    for (int rb = 0; rb < 3; ++rb)
                        cp16(gx16 + ((long)t * BP + m0 + rb * 32 + (l >> 1)) * 3072 + g * H_ + n0 + (l & 1) * 8,
                             (void*)(gxlds + (g * 96 + rb * 32) * 16));
            }
            __syncthreads();
        }
        // in-register epilogue on waves 0-2 (C-layout: row=rowq+r, col=colq, tile w*2+mi)
        if (w < 3) {
#pragma unroll
            for (int mi = 0; mi < 2; ++mi)
#pragma unroll
                for (int r = 0; r < 4; ++r) {
                    int m = (w * 2 + mi) * 16 + rowq + r;
                    int mg = m0 + m;
                    float xr = (float)gxlds[(0 * 96 + m) * 16 + colq];
                    float xz = (float)gxlds[(1 * 96 + m) * 16 + colq];
                    float xn = (float)gxlds[(2 * 96 + m) * 16 + colq];
                    float r_ = fast_sig(xr + acc[0][mi][r] + bhr);
                    float z_ = fast_sig(xz + acc[1][mi][r] + bhz);
                    float n_ = fast_tanh(xn + r_ * (acc[2][mi][r] + bhn));
                    float hnew = (1.f - z_) * n_ + z_ * hprev[mi][r];
                    hprev[mi][r] = hnew;
                    hout[mg * H_ + col] = (f16)hnew;
                    int b = mg / P_, p = mg % P_;
                    hid16[(((long)b * T_ + t) * P_ + p) * H_ + col] = (f16)hnew;
                }
        }
        if (t != T_ - 1) {
            // custom grid barrier: release-add + acquire-spin, per-step counter
            __syncthreads();
            if (tid == 0) {
                int* c = bar + t * 16;      // 64B-padded per step
                __hip_atomic_fetch_add(c, 1, __ATOMIC_RELEASE, __HIP_MEMORY_SCOPE_AGENT);
                while (__hip_atomic_load(c, __ATOMIC_ACQUIRE, __HIP_MEMORY_SCOPE_AGENT) < 256)
                    __builtin_amdgcn_s_sleep(1);
            }
            __syncthreads();
        }
    }
}

// ---- per-(b,t): 12x9 action logits, maxpool over P, 8 activity logits ----
__global__ __launch_bounds__(256) void logits_kernel(const f16* __restrict__ hid16,
                                                     const float* __restrict__ W_act,
                                                     const float* __restrict__ b_act,
                                                     const float* __restrict__ W_activ,
                                                     const float* __restrict__ b_activ,
                                                     float* __restrict__ out) {
    __shared__ f16 hs[P_ * H_];
    __shared__ float pooled[H_];
    const int bt = blockIdx.x;           // b*T_ + t
    const int tid = threadIdx.x, w = tid >> 6, l = tid & 63;

    const f16x8* src = (const f16x8*)(hid16 + (long)bt * P_ * H_);
    f16x8* dst = (f16x8*)hs;
    for (int i = tid; i < P_ * H_ / 8; i += 256) dst[i] = src[i];
    __syncthreads();

    for (int i = tid; i < H_; i += 256) {
        float mx = (float)hs[i];
#pragma unroll
        for (int p = 1; p < P_; ++p) mx = fmaxf(mx, (float)hs[p * H_ + i]);
        pooled[i] = mx;
    }
    __syncthreads();

    for (int j = w; j < 108; j += 4) {
        int p = j / 9, a = j % 9;
        float s = 0.f;
#pragma unroll
        for (int it = 0; it < 16; ++it) {
            int idx = l + it * 64;
            s += (float)hs[p * H_ + idx] * W_act[a * H_ + idx];
        }
#pragma unroll
        for (int off = 32; off > 0; off >>= 1) s += __shfl_down(s, off);
        if (l == 0) out[((long)bt * P_ + p) * 9 + a] = s + b_act[a];
    }
    for (int j = w; j < 8; j += 4) {
        float s = 0.f;
#pragma unroll
        for (int it = 0; it < 16; ++it) {
            int idx = l + it * 64;
            s += pooled[idx] * W_activ[j * H_ + idx];
        }
#pragma unroll
        for (int off = 32; off > 0; off >>= 1) s += __shfl_down(s, off);
        if (l == 0) out[(long)M_ * 9 + (long)bt * 8 + j] = s + b_activ[j];
    }
}

extern "C" void kernel_launch(void* const* d_in, const int* in_sizes, int n_in,
                              void* d_out, int out_size, void* d_ws, size_t ws_size,
                              hipStream_t stream) {
    const float* feature = (const float*)d_in[0];
    const float* W_embed = (const float*)d_in[1];
    const float* b_embed = (const float*)d_in[2];
    const float* W_ih    = (const float*)d_in[3];
    const float* W_hh    = (const float*)d_in[4];
    const float* b_ih    = (const float*)d_in[5];
    const float* b_hh    = (const float*)d_in[6];
    const float* W_act   = (const float*)d_in[7];
    const float* b_act   = (const float*)d_in[8];
    const float* W_activ = (const float*)d_in[9];
    const float* b_activ = (const float*)d_in[10];
    float* out = (float*)d_out;

    char* ws = (char*)d_ws;
    size_t off = 0;
    auto alloc = [&](size_t bytes) {
        void* p = ws + off;
        off = (off + bytes + 255) & ~(size_t)255;
        return p;
    };
    f16* feat16 = (f16*)alloc((size_t)M_ * E_ * 2);        // 62.9 MB
    f16* wE16   = (f16*)alloc((size_t)H_ * E_ * 2);        //  4.2 MB
    f16* wIH16  = (f16*)alloc((size_t)3 * H_ * H_ * 2);    //  6.3 MB
    f16* wHH16  = (f16*)alloc((size_t)3 * H_ * H_ * 2);    //  6.3 MB
    f16* x16    = (f16*)alloc((size_t)M_ * H_ * 2);        // 31.5 MB
    f16* gx16   = (f16*)alloc((size_t)M_ * 3 * H_ * 2);    // 94.4 MB
    f16* hbuf   = (f16*)alloc((size_t)2 * BP * H_ * 2);    //  1.5 MB
    f16* hid16  = (f16*)alloc((size_t)M_ * H_ * 2);        // 31.5 MB
    int* bar    = (int*)alloc((size_t)T_ * 16 * 4);        //  2.5 KB barrier counters
    (void)ws_size; (void)in_sizes; (void)n_in; (void)out_size;

    hipMemsetAsync(bar, 0, (size_t)T_ * 16 * 4, stream);   // ws is re-poisoned 0xAA

    cvt_f32_f16<<<(M_ * E_) / 2048, 256, 0, stream>>>(feature, feat16, (M_ * E_) / 8);
    cvt_f32_f16<<<(H_ * E_) / 2048, 256, 0, stream>>>(W_embed, wE16, (H_ * E_) / 8);
    cvt_f32_f16<<<(3 * H_ * H_) / 2048, 256, 0, stream>>>(W_ih, wIH16, (3 * H_ * H_) / 8);
    cvt_f32_f16<<<(3 * H_ * H_) / 2048, 256, 0, stream>>>(W_hh, wHH16, (3 * H_ * H_) / 8);

    gemm128<0><<<dim3(M_ / 128, H_ / 128), 256, 0, stream>>>(feat16, wE16, b_embed, x16, E_, H_);
    gemm128<1><<<dim3(M_ / 128, (3 * H_) / 128), 256, 0, stream>>>(x16, wIH16, b_ih, gx16, H_, 3 * H_);

    void* args[] = {(void*)&gx16, (void*)&wHH16, (void*)&b_hh, (void*)&hbuf,
                    (void*)&hid16, (void*)&bar};
    hipLaunchCooperativeKernel((const void*)gru_persist, dim3(256), dim3(256), args, 0, stream);

    logits_kernel<<<B_ * T_, 256, 0, stream>>>(hid16, W_act, b_act, W_activ, b_activ, out);
}